// Round 1
// baseline (959.994 us; speedup 1.0000x reference)
//
#include <hip/hip_runtime.h>
#include <math.h>

// Problem constants (from reference): N=100000, E=1600000, D_IN=D_H=128, D_OUT=47
#define DH 128
#define DOUT 47
#define BN_EPS 1e-5f

// ---------------------------------------------------------------------------
// CSR build: counts -> scan -> fill
// ---------------------------------------------------------------------------

__global__ void zero_int_k(int* __restrict__ p, int n) {
    int i = blockIdx.x * 256 + threadIdx.x;
    if (i < n) p[i] = 0;
}

__global__ void count_k(const int* __restrict__ dst, int* __restrict__ counts,
                        int e, int n) {
    int i = blockIdx.x * 256 + threadIdx.x;
    int stride = gridDim.x * 256;
    for (; i < e; i += stride) {
        int d = dst[i];
        if ((unsigned)d < (unsigned)n) atomicAdd(&counts[d], 1);
    }
}

// scan1: per-1024-chunk exclusive scan; writes chunk-local exclusive prefix +
// per-block totals.
__global__ __launch_bounds__(256) void scan1_k(const int* __restrict__ counts,
                                               int* __restrict__ offsets,
                                               int* __restrict__ blocksums, int n) {
    __shared__ int sd[256];
    int tid = threadIdx.x;
    int base = blockIdx.x * 1024 + tid * 4;
    int v0 = (base + 0 < n) ? counts[base + 0] : 0;
    int v1 = (base + 1 < n) ? counts[base + 1] : 0;
    int v2 = (base + 2 < n) ? counts[base + 2] : 0;
    int v3 = (base + 3 < n) ? counts[base + 3] : 0;
    int tsum = v0 + v1 + v2 + v3;
    sd[tid] = tsum;
    __syncthreads();
    // Hillis-Steele inclusive scan over 256 thread sums
    for (int off = 1; off < 256; off <<= 1) {
        int x = (tid >= off) ? sd[tid - off] : 0;
        __syncthreads();
        sd[tid] += x;
        __syncthreads();
    }
    if (tid == 255) blocksums[blockIdx.x] = sd[255];
    int run = sd[tid] - tsum;   // exclusive prefix for this thread's 4 elems
    if (base + 0 < n) offsets[base + 0] = run;  run += v0;
    if (base + 1 < n) offsets[base + 1] = run;  run += v1;
    if (base + 2 < n) offsets[base + 2] = run;  run += v2;
    if (base + 3 < n) offsets[base + 3] = run;
}

// scan2: exclusive scan over <=128 block sums, in-place (single block, 128 thr)
__global__ __launch_bounds__(128) void scan2_k(int* __restrict__ blocksums, int nb) {
    __shared__ int sd[128];
    int tid = threadIdx.x;
    int v = (tid < nb) ? blocksums[tid] : 0;
    sd[tid] = v;
    __syncthreads();
    for (int off = 1; off < 128; off <<= 1) {
        int x = (tid >= off) ? sd[tid - off] : 0;
        __syncthreads();
        sd[tid] += x;
        __syncthreads();
    }
    if (tid < nb) blocksums[tid] = sd[tid] - v;  // exclusive
}

// finalize: add chunk base offsets, init cursor, compute dinv = rsqrt(indeg+1)
__global__ void finalize_k(int* __restrict__ offsets, int* __restrict__ cursor,
                           float* __restrict__ dinv, const int* __restrict__ counts,
                           const int* __restrict__ blocksums, int n) {
    int i = blockIdx.x * 256 + threadIdx.x;
    if (i >= n) return;
    int o = offsets[i] + blocksums[i >> 10];
    offsets[i] = o;
    cursor[i] = o;
    dinv[i] = rsqrtf((float)(counts[i] + 1));  // +1 self-loop; deg>=1 always
}

__global__ void fill_k(const int* __restrict__ src, const int* __restrict__ dst,
                       int* __restrict__ cursor, int* __restrict__ elist,
                       int e, int n) {
    int i = blockIdx.x * 256 + threadIdx.x;
    int stride = gridDim.x * 256;
    for (; i < e; i += stride) {
        int d = dst[i];
        if ((unsigned)d < (unsigned)n) {
            int pos = atomicAdd(&cursor[d], 1);
            elist[pos] = src[i];
        }
    }
}

// ---------------------------------------------------------------------------
// fp32 GEMM: C[M x 128] = A[M x 128] @ B[128 x 128]   (vector ALU; no fp32 MFMA)
// Block: 256 threads, 64 rows x 128 cols tile, K-panels of 32.
// ---------------------------------------------------------------------------
#define FMA4(c, s, b) \
    c.x = fmaf(s, b.x, c.x); c.y = fmaf(s, b.y, c.y); \
    c.z = fmaf(s, b.z, c.z); c.w = fmaf(s, b.w, c.w);

__global__ __launch_bounds__(256) void gemm128_k(const float* __restrict__ A,
                                                 const float* __restrict__ B,
                                                 float* __restrict__ C, int M) {
    __shared__ __align__(16) float As[64][32];
    __shared__ __align__(16) float Bs[32][128];
    int tid = threadIdx.x;
    int r0 = blockIdx.x * 64;
    int tx = tid & 31;   // col group: cols [4*tx, 4*tx+4)
    int ty = tid >> 5;   // row group: rows [8*ty, 8*ty+8)
    float4 acc[8];
#pragma unroll
    for (int j = 0; j < 8; j++) acc[j] = make_float4(0.f, 0.f, 0.f, 0.f);

    for (int kk = 0; kk < 128; kk += 32) {
        // stage A panel: 64x32 = 512 float4
        for (int l = tid; l < 512; l += 256) {
            int r = l >> 3;
            int c4 = (l & 7) << 2;
            int row = r0 + r;
            float4 v = make_float4(0.f, 0.f, 0.f, 0.f);
            if (row < M) v = *(const float4*)(A + (size_t)row * 128 + kk + c4);
            *(float4*)(&As[r][c4]) = v;
        }
        // stage B panel: 32x128 = 1024 float4
        for (int l = tid; l < 1024; l += 256) {
            int r = l >> 5;
            int c4 = (l & 31) << 2;
            *(float4*)(&Bs[r][c4]) = *(const float4*)(B + (size_t)(kk + r) * 128 + c4);
        }
        __syncthreads();
#pragma unroll
        for (int k = 0; k < 32; k += 4) {
            float4 b0 = *(const float4*)(&Bs[k + 0][tx << 2]);
            float4 b1 = *(const float4*)(&Bs[k + 1][tx << 2]);
            float4 b2 = *(const float4*)(&Bs[k + 2][tx << 2]);
            float4 b3 = *(const float4*)(&Bs[k + 3][tx << 2]);
#pragma unroll
            for (int j = 0; j < 8; j++) {
                float4 a = *(const float4*)(&As[ty * 8 + j][k]);
                float4 c = acc[j];
                FMA4(c, a.x, b0); FMA4(c, a.y, b1);
                FMA4(c, a.z, b2); FMA4(c, a.w, b3);
                acc[j] = c;
            }
        }
        __syncthreads();
    }
#pragma unroll
    for (int j = 0; j < 8; j++) {
        int row = r0 + ty * 8 + j;
        if (row < M) *(float4*)(C + (size_t)row * 128 + (tx << 2)) = acc[j];
    }
}

// ---------------------------------------------------------------------------
// Aggregation (pull over CSR-by-dst). 128 threads per node (1 feature/thread).
// Layer 1 variant: + b1, BN(eval), ReLU -> H1
// ---------------------------------------------------------------------------
__global__ __launch_bounds__(256) void agg1_k(
    const float* __restrict__ H, const int* __restrict__ elist,
    const int* __restrict__ offsets, const int* __restrict__ counts,
    const float* __restrict__ dinv, const float* __restrict__ b1,
    const float* __restrict__ gamma, const float* __restrict__ beta,
    const float* __restrict__ mean, const float* __restrict__ var,
    float* __restrict__ H1, int n) {
    int t = threadIdx.x & 127;
    int node = blockIdx.x * 2 + (threadIdx.x >> 7);
    if (node >= n) return;
    float di = dinv[node];
    int start = offsets[node];
    int cnt = counts[node];
    float acc = H[(size_t)node * 128 + t] * di * di;  // self-loop
    if (cnt > 0) {
        int s_nxt = elist[start];
        for (int j = 0; j < cnt; j++) {
            int s = s_nxt;
            if (j + 1 < cnt) s_nxt = elist[start + j + 1];
            float w = dinv[s] * di;
            acc = fmaf(H[(size_t)s * 128 + t], w, acc);
        }
    }
    float v = (acc + b1[t] - mean[t]) * rsqrtf(var[t] + BN_EPS) * gamma[t] + beta[t];
    H1[(size_t)node * 128 + t] = fmaxf(v, 0.f);
}

// Layer 2 variant: + b2, then JK max with H1 (in-place over H1 -> JK)
__global__ __launch_bounds__(256) void agg2_k(
    const float* __restrict__ H, const int* __restrict__ elist,
    const int* __restrict__ offsets, const int* __restrict__ counts,
    const float* __restrict__ dinv, const float* __restrict__ b2,
    float* __restrict__ H1JK, int n) {
    int t = threadIdx.x & 127;
    int node = blockIdx.x * 2 + (threadIdx.x >> 7);
    if (node >= n) return;
    float di = dinv[node];
    int start = offsets[node];
    int cnt = counts[node];
    float acc = H[(size_t)node * 128 + t] * di * di;
    if (cnt > 0) {
        int s_nxt = elist[start];
        for (int j = 0; j < cnt; j++) {
            int s = s_nxt;
            if (j + 1 < cnt) s_nxt = elist[start + j + 1];
            float w = dinv[s] * di;
            acc = fmaf(H[(size_t)s * 128 + t], w, acc);
        }
    }
    float h2 = acc + b2[t];
    size_t idx = (size_t)node * 128 + t;
    H1JK[idx] = fmaxf(H1JK[idx], h2);  // jk = max(h1, h2); own-row only, race-free
}

// ---------------------------------------------------------------------------
// Head: logits = jk @ Wf + bf, then log_softmax over 47 classes.
// 256 threads = 4 waves = 4 nodes/block. Wf staged in LDS (128*47*4 = 24 KB).
// ---------------------------------------------------------------------------
__global__ __launch_bounds__(256) void head_k(const float* __restrict__ JK,
                                              const float* __restrict__ Wf,
                                              const float* __restrict__ bf,
                                              float* __restrict__ out, int n) {
    __shared__ float Ws[128 * DOUT];
    __shared__ float row[4][128];
    int tid = threadIdx.x;
    for (int l = tid; l < 128 * DOUT; l += 256) Ws[l] = Wf[l];
    int wave = tid >> 6, lane = tid & 63;
    int node = blockIdx.x * 4 + wave;
    if (node < n) {
        row[wave][lane]      = JK[(size_t)node * 128 + lane];
        row[wave][lane + 64] = JK[(size_t)node * 128 + lane + 64];
    }
    __syncthreads();
    if (node >= n) return;

    float acc = (lane < DOUT) ? bf[lane] : 0.f;
#pragma unroll 8
    for (int k = 0; k < 128; k++) {
        float xv = row[wave][k];
        float w = (lane < DOUT) ? Ws[k * DOUT + lane] : 0.f;
        acc = fmaf(xv, w, acc);
    }
    // log-softmax over lanes [0,47)
    float v = (lane < DOUT) ? acc : -INFINITY;
    float m = v;
    for (int off = 32; off >= 1; off >>= 1) m = fmaxf(m, __shfl_down(m, off));
    m = __shfl(m, 0);
    float e = (lane < DOUT) ? expf(acc - m) : 0.f;
    float s = e;
    for (int off = 32; off >= 1; off >>= 1) s += __shfl_down(s, off);
    s = __shfl(s, 0);
    float ls = logf(s);
    if (lane < DOUT) out[(size_t)node * DOUT + lane] = acc - m - ls;
}

// ---------------------------------------------------------------------------
extern "C" void kernel_launch(void* const* d_in, const int* in_sizes, int n_in,
                              void* d_out, int out_size, void* d_ws, size_t ws_size,
                              hipStream_t stream) {
    const float* x     = (const float*)d_in[0];
    const int*   ei    = (const int*)d_in[1];
    const float* W1    = (const float*)d_in[2];
    const float* b1    = (const float*)d_in[3];
    const float* gamma = (const float*)d_in[4];
    const float* beta  = (const float*)d_in[5];
    const float* mean  = (const float*)d_in[6];
    const float* var   = (const float*)d_in[7];
    const float* W2    = (const float*)d_in[8];
    const float* b2    = (const float*)d_in[9];
    const float* Wf    = (const float*)d_in[10];
    const float* bf    = (const float*)d_in[11];
    float* out = (float*)d_out;

    int N_ = in_sizes[0] / 128;
    int E_ = in_sizes[1] / 2;
    const int* src = ei;
    const int* dst = ei + E_;

    char* ws = (char*)d_ws;
    float* bufA    = (float*)ws;  ws += (size_t)N_ * 128 * 4;
    float* h1      = (float*)ws;  ws += (size_t)N_ * 128 * 4;
    int*   counts  = (int*)ws;    ws += (size_t)N_ * 4;
    int*   offsets = (int*)ws;    ws += (size_t)N_ * 4;
    int*   cursor  = (int*)ws;    ws += (size_t)N_ * 4;
    float* dinv    = (float*)ws;  ws += (size_t)N_ * 4;
    int*   elist   = (int*)ws;    ws += (size_t)E_ * 4;
    int*   bsums   = (int*)ws;    ws += 1024 * 4;

    int nb = (N_ + 1023) / 1024;  // 98 chunks; scan2 handles <=128

    zero_int_k<<<(N_ + 255) / 256, 256, 0, stream>>>(counts, N_);
    count_k<<<2048, 256, 0, stream>>>(dst, counts, E_, N_);
    scan1_k<<<nb, 256, 0, stream>>>(counts, offsets, bsums, N_);
    scan2_k<<<1, 128, 0, stream>>>(bsums, nb);
    finalize_k<<<(N_ + 255) / 256, 256, 0, stream>>>(offsets, cursor, dinv, counts, bsums, N_);
    fill_k<<<2048, 256, 0, stream>>>(src, dst, cursor, elist, E_, N_);

    // layer 1
    gemm128_k<<<(N_ + 63) / 64, 256, 0, stream>>>(x, W1, bufA, N_);
    agg1_k<<<(N_ + 1) / 2, 256, 0, stream>>>(bufA, elist, offsets, counts, dinv,
                                             b1, gamma, beta, mean, var, h1, N_);
    // layer 2 (reuse bufA)
    gemm128_k<<<(N_ + 63) / 64, 256, 0, stream>>>(h1, W2, bufA, N_);
    agg2_k<<<(N_ + 1) / 2, 256, 0, stream>>>(bufA, elist, offsets, counts, dinv,
                                             b2, h1, N_);
    // head: h1 now holds jk = max(h1, h2)
    head_k<<<(N_ + 3) / 4, 256, 0, stream>>>(h1, Wf, bf, out, N_);
}

// Round 2
// 745.397 us; speedup vs baseline: 1.2879x; 1.2879x over previous
//
#include <hip/hip_runtime.h>
#include <math.h>

// Problem constants (from reference): N=100000, E=1600000, D_IN=D_H=128, D_OUT=47
#define DH 128
#define DOUT 47
#define BN_EPS 1e-5f

// ---------------------------------------------------------------------------
// CSR build: counts -> scan -> fill (with fused edge-weight precompute)
// ---------------------------------------------------------------------------

__global__ void zero_int_k(int* __restrict__ p, int n) {
    int i = blockIdx.x * 256 + threadIdx.x;
    if (i < n) p[i] = 0;
}

__global__ void count_k(const int* __restrict__ dst, int* __restrict__ counts,
                        int e, int n) {
    int i = blockIdx.x * 256 + threadIdx.x;
    int stride = gridDim.x * 256;
    for (; i < e; i += stride) {
        int d = dst[i];
        if ((unsigned)d < (unsigned)n) atomicAdd(&counts[d], 1);
    }
}

// scan1: per-1024-chunk exclusive scan; writes chunk-local exclusive prefix +
// per-block totals.
__global__ __launch_bounds__(256) void scan1_k(const int* __restrict__ counts,
                                               int* __restrict__ offsets,
                                               int* __restrict__ blocksums, int n) {
    __shared__ int sd[256];
    int tid = threadIdx.x;
    int base = blockIdx.x * 1024 + tid * 4;
    int v0 = (base + 0 < n) ? counts[base + 0] : 0;
    int v1 = (base + 1 < n) ? counts[base + 1] : 0;
    int v2 = (base + 2 < n) ? counts[base + 2] : 0;
    int v3 = (base + 3 < n) ? counts[base + 3] : 0;
    int tsum = v0 + v1 + v2 + v3;
    sd[tid] = tsum;
    __syncthreads();
    for (int off = 1; off < 256; off <<= 1) {
        int x = (tid >= off) ? sd[tid - off] : 0;
        __syncthreads();
        sd[tid] += x;
        __syncthreads();
    }
    if (tid == 255) blocksums[blockIdx.x] = sd[255];
    int run = sd[tid] - tsum;
    if (base + 0 < n) offsets[base + 0] = run;  run += v0;
    if (base + 1 < n) offsets[base + 1] = run;  run += v1;
    if (base + 2 < n) offsets[base + 2] = run;  run += v2;
    if (base + 3 < n) offsets[base + 3] = run;
}

__global__ __launch_bounds__(128) void scan2_k(int* __restrict__ blocksums, int nb) {
    __shared__ int sd[128];
    int tid = threadIdx.x;
    int v = (tid < nb) ? blocksums[tid] : 0;
    sd[tid] = v;
    __syncthreads();
    for (int off = 1; off < 128; off <<= 1) {
        int x = (tid >= off) ? sd[tid - off] : 0;
        __syncthreads();
        sd[tid] += x;
        __syncthreads();
    }
    if (tid < nb) blocksums[tid] = sd[tid] - v;  // exclusive
}

__global__ void finalize_k(int* __restrict__ offsets, int* __restrict__ cursor,
                           float* __restrict__ dinv, const int* __restrict__ counts,
                           const int* __restrict__ blocksums, int n) {
    int i = blockIdx.x * 256 + threadIdx.x;
    if (i >= n) return;
    int o = offsets[i] + blocksums[i >> 10];
    offsets[i] = o;
    cursor[i] = o;
    dinv[i] = rsqrtf((float)(counts[i] + 1));  // +1 self-loop; deg>=1 always
}

// fill: edge record = (src, dinv[src]*dinv[dst]) packed in 8 B.
// Removes the per-edge dinv gather from BOTH aggregation kernels.
__global__ void fill_k(const int* __restrict__ src, const int* __restrict__ dst,
                       const float* __restrict__ dinv, int* __restrict__ cursor,
                       int2* __restrict__ ew, int e, int n) {
    int i = blockIdx.x * 256 + threadIdx.x;
    int stride = gridDim.x * 256;
    for (; i < e; i += stride) {
        int d = dst[i];
        if ((unsigned)d < (unsigned)n) {
            int s = src[i];
            int pos = atomicAdd(&cursor[d], 1);
            int2 rec;
            rec.x = s;
            rec.y = __float_as_int(dinv[s] * dinv[d]);
            ew[pos] = rec;
        }
    }
}

// ---------------------------------------------------------------------------
// fp32 GEMM: C[M x 128] = A[M x 128] @ B[128 x 128]   (vector ALU; no fp32 MFMA)
// ---------------------------------------------------------------------------
#define FMA4(c, s, b) \
    c.x = fmaf(s, b.x, c.x); c.y = fmaf(s, b.y, c.y); \
    c.z = fmaf(s, b.z, c.z); c.w = fmaf(s, b.w, c.w);

__global__ __launch_bounds__(256) void gemm128_k(const float* __restrict__ A,
                                                 const float* __restrict__ B,
                                                 float* __restrict__ C, int M) {
    __shared__ __align__(16) float As[64][32];
    __shared__ __align__(16) float Bs[32][128];
    int tid = threadIdx.x;
    int r0 = blockIdx.x * 64;
    int tx = tid & 31;
    int ty = tid >> 5;
    float4 acc[8];
#pragma unroll
    for (int j = 0; j < 8; j++) acc[j] = make_float4(0.f, 0.f, 0.f, 0.f);

    for (int kk = 0; kk < 128; kk += 32) {
        for (int l = tid; l < 512; l += 256) {
            int r = l >> 3;
            int c4 = (l & 7) << 2;
            int row = r0 + r;
            float4 v = make_float4(0.f, 0.f, 0.f, 0.f);
            if (row < M) v = *(const float4*)(A + (size_t)row * 128 + kk + c4);
            *(float4*)(&As[r][c4]) = v;
        }
        for (int l = tid; l < 1024; l += 256) {
            int r = l >> 5;
            int c4 = (l & 31) << 2;
            *(float4*)(&Bs[r][c4]) = *(const float4*)(B + (size_t)(kk + r) * 128 + c4);
        }
        __syncthreads();
#pragma unroll
        for (int k = 0; k < 32; k += 4) {
            float4 b0 = *(const float4*)(&Bs[k + 0][tx << 2]);
            float4 b1 = *(const float4*)(&Bs[k + 1][tx << 2]);
            float4 b2 = *(const float4*)(&Bs[k + 2][tx << 2]);
            float4 b3 = *(const float4*)(&Bs[k + 3][tx << 2]);
#pragma unroll
            for (int j = 0; j < 8; j++) {
                float4 a = *(const float4*)(&As[ty * 8 + j][k]);
                float4 c = acc[j];
                FMA4(c, a.x, b0); FMA4(c, a.y, b1);
                FMA4(c, a.z, b2); FMA4(c, a.w, b3);
                acc[j] = c;
            }
        }
        __syncthreads();
    }
#pragma unroll
    for (int j = 0; j < 8; j++) {
        int row = r0 + ty * 8 + j;
        if (row < M) *(float4*)(C + (size_t)row * 128 + (tx << 2)) = acc[j];
    }
}

// ---------------------------------------------------------------------------
// Aggregation: one 64-lane wave per node, float2 per lane (whole 512 B row in
// one dwordx2 per wave), edges unrolled x4 for memory-level parallelism.
// Edge records (src, weight) are uniform-address 8 B loads (broadcast).
// ---------------------------------------------------------------------------

#define AGG_BODY(H, ew, offsets, counts, dinv)                              \
    int lane = threadIdx.x & 63;                                            \
    int node = blockIdx.x * 4 + (threadIdx.x >> 6);                         \
    if (node >= n) return;                                                  \
    float di = dinv[node];                                                  \
    int start = offsets[node];                                              \
    int cnt = counts[node];                                                 \
    const float2* __restrict__ Hrow = (const float2*)H;                     \
    float2 self = Hrow[(size_t)node * 64 + lane];                           \
    float wself = di * di;                                                  \
    float2 acc = make_float2(self.x * wself, self.y * wself);               \
    int j = 0;                                                              \
    for (; j + 4 <= cnt; j += 4) {                                          \
        int2 e0 = ew[start + j + 0];                                        \
        int2 e1 = ew[start + j + 1];                                        \
        int2 e2 = ew[start + j + 2];                                        \
        int2 e3 = ew[start + j + 3];                                        \
        float2 f0 = Hrow[(size_t)e0.x * 64 + lane];                         \
        float2 f1 = Hrow[(size_t)e1.x * 64 + lane];                         \
        float2 f2 = Hrow[(size_t)e2.x * 64 + lane];                         \
        float2 f3 = Hrow[(size_t)e3.x * 64 + lane];                         \
        float w0 = __int_as_float(e0.y), w1 = __int_as_float(e1.y);         \
        float w2 = __int_as_float(e2.y), w3 = __int_as_float(e3.y);         \
        acc.x = fmaf(f0.x, w0, acc.x); acc.y = fmaf(f0.y, w0, acc.y);       \
        acc.x = fmaf(f1.x, w1, acc.x); acc.y = fmaf(f1.y, w1, acc.y);       \
        acc.x = fmaf(f2.x, w2, acc.x); acc.y = fmaf(f2.y, w2, acc.y);       \
        acc.x = fmaf(f3.x, w3, acc.x); acc.y = fmaf(f3.y, w3, acc.y);       \
    }                                                                       \
    for (; j < cnt; j++) {                                                  \
        int2 e = ew[start + j];                                             \
        float2 f = Hrow[(size_t)e.x * 64 + lane];                          \
        float w = __int_as_float(e.y);                                      \
        acc.x = fmaf(f.x, w, acc.x); acc.y = fmaf(f.y, w, acc.y);           \
    }

// Layer 1: + b1, BN(eval), ReLU -> H1
__global__ __launch_bounds__(256) void agg1_k(
    const float* __restrict__ H, const int2* __restrict__ ew,
    const int* __restrict__ offsets, const int* __restrict__ counts,
    const float* __restrict__ dinv, const float* __restrict__ b1,
    const float* __restrict__ gamma, const float* __restrict__ beta,
    const float* __restrict__ mean, const float* __restrict__ var,
    float* __restrict__ H1, int n) {
    AGG_BODY(H, ew, offsets, counts, dinv)
    int t0 = lane * 2;
    float2 bb = *(const float2*)(b1 + t0);
    float2 mm = *(const float2*)(mean + t0);
    float2 vv = *(const float2*)(var + t0);
    float2 gg = *(const float2*)(gamma + t0);
    float2 be = *(const float2*)(beta + t0);
    float vx = (acc.x + bb.x - mm.x) * rsqrtf(vv.x + BN_EPS) * gg.x + be.x;
    float vy = (acc.y + bb.y - mm.y) * rsqrtf(vv.y + BN_EPS) * gg.y + be.y;
    float2 outv = make_float2(fmaxf(vx, 0.f), fmaxf(vy, 0.f));
    *(float2*)(H1 + (size_t)node * 128 + t0) = outv;
}

// Layer 2: + b2, then JK max with H1 (in-place H1 -> JK)
__global__ __launch_bounds__(256) void agg2_k(
    const float* __restrict__ H, const int2* __restrict__ ew,
    const int* __restrict__ offsets, const int* __restrict__ counts,
    const float* __restrict__ dinv, const float* __restrict__ b2,
    float* __restrict__ H1JK, int n) {
    AGG_BODY(H, ew, offsets, counts, dinv)
    int t0 = lane * 2;
    float2 bb = *(const float2*)(b2 + t0);
    float2* p = (float2*)(H1JK + (size_t)node * 128 + t0);
    float2 h1v = *p;
    float2 outv = make_float2(fmaxf(h1v.x, acc.x + bb.x),
                              fmaxf(h1v.y, acc.y + bb.y));
    *p = outv;
}

// ---------------------------------------------------------------------------
// Head: logits = jk @ Wf + bf, then log_softmax over 47 classes.
// ---------------------------------------------------------------------------
__global__ __launch_bounds__(256) void head_k(const float* __restrict__ JK,
                                              const float* __restrict__ Wf,
                                              const float* __restrict__ bf,
                                              float* __restrict__ out, int n) {
    __shared__ float Ws[128 * DOUT];
    __shared__ float row[4][128];
    int tid = threadIdx.x;
    for (int l = tid; l < 128 * DOUT; l += 256) Ws[l] = Wf[l];
    int wave = tid >> 6, lane = tid & 63;
    int node = blockIdx.x * 4 + wave;
    if (node < n) {
        row[wave][lane]      = JK[(size_t)node * 128 + lane];
        row[wave][lane + 64] = JK[(size_t)node * 128 + lane + 64];
    }
    __syncthreads();
    if (node >= n) return;

    float acc = (lane < DOUT) ? bf[lane] : 0.f;
#pragma unroll 8
    for (int k = 0; k < 128; k++) {
        float xv = row[wave][k];
        float w = (lane < DOUT) ? Ws[k * DOUT + lane] : 0.f;
        acc = fmaf(xv, w, acc);
    }
    float v = (lane < DOUT) ? acc : -INFINITY;
    float m = v;
    for (int off = 32; off >= 1; off >>= 1) m = fmaxf(m, __shfl_down(m, off));
    m = __shfl(m, 0);
    float e = (lane < DOUT) ? expf(acc - m) : 0.f;
    float s = e;
    for (int off = 32; off >= 1; off >>= 1) s += __shfl_down(s, off);
    s = __shfl(s, 0);
    float ls = logf(s);
    if (lane < DOUT) out[(size_t)node * DOUT + lane] = acc - m - ls;
}

// ---------------------------------------------------------------------------
extern "C" void kernel_launch(void* const* d_in, const int* in_sizes, int n_in,
                              void* d_out, int out_size, void* d_ws, size_t ws_size,
                              hipStream_t stream) {
    const float* x     = (const float*)d_in[0];
    const int*   ei    = (const int*)d_in[1];
    const float* W1    = (const float*)d_in[2];
    const float* b1    = (const float*)d_in[3];
    const float* gamma = (const float*)d_in[4];
    const float* beta  = (const float*)d_in[5];
    const float* mean  = (const float*)d_in[6];
    const float* var   = (const float*)d_in[7];
    const float* W2    = (const float*)d_in[8];
    const float* b2    = (const float*)d_in[9];
    const float* Wf    = (const float*)d_in[10];
    const float* bf    = (const float*)d_in[11];
    float* out = (float*)d_out;

    int N_ = in_sizes[0] / 128;
    int E_ = in_sizes[1] / 2;
    const int* src = ei;
    const int* dst = ei + E_;

    char* ws = (char*)d_ws;
    float* bufA    = (float*)ws;  ws += (size_t)N_ * 128 * 4;
    float* h1      = (float*)ws;  ws += (size_t)N_ * 128 * 4;
    int*   counts  = (int*)ws;    ws += (size_t)N_ * 4;
    int*   offsets = (int*)ws;    ws += (size_t)N_ * 4;
    int*   cursor  = (int*)ws;    ws += (size_t)N_ * 4;
    float* dinv    = (float*)ws;  ws += (size_t)N_ * 4;
    int2*  ew      = (int2*)ws;   ws += (size_t)E_ * 8;
    int*   bsums   = (int*)ws;    ws += 1024 * 4;

    int nb = (N_ + 1023) / 1024;

    zero_int_k<<<(N_ + 255) / 256, 256, 0, stream>>>(counts, N_);
    count_k<<<2048, 256, 0, stream>>>(dst, counts, E_, N_);
    scan1_k<<<nb, 256, 0, stream>>>(counts, offsets, bsums, N_);
    scan2_k<<<1, 128, 0, stream>>>(bsums, nb);
    finalize_k<<<(N_ + 255) / 256, 256, 0, stream>>>(offsets, cursor, dinv, counts, bsums, N_);
    fill_k<<<2048, 256, 0, stream>>>(src, dst, dinv, cursor, ew, E_, N_);

    // layer 1
    gemm128_k<<<(N_ + 63) / 64, 256, 0, stream>>>(x, W1, bufA, N_);
    agg1_k<<<(N_ + 3) / 4, 256, 0, stream>>>(bufA, ew, offsets, counts, dinv,
                                             b1, gamma, beta, mean, var, h1, N_);
    // layer 2 (reuse bufA)
    gemm128_k<<<(N_ + 63) / 64, 256, 0, stream>>>(h1, W2, bufA, N_);
    agg2_k<<<(N_ + 3) / 4, 256, 0, stream>>>(bufA, ew, offsets, counts, dinv,
                                             b2, h1, N_);
    // head: h1 now holds jk = max(h1, h2)
    head_k<<<(N_ + 3) / 4, 256, 0, stream>>>(h1, Wf, bf, out, N_);
}